// Round 2
// baseline (970654.492 us; speedup 1.0000x reference)
//
#include <hip/hip_runtime.h>
#include <math.h>

// Deep Reservoir Memory Network forward, MI355X persistent-dataflow kernel.
// Round 2: weights-in-LDS + register-pipelined coherent state reads.
//
// Round-1 post-mortem: 309 ms, VALUBusy 9.8%, 40 GB HBM fetch = weights
// thrashing per-XCD L2 every tick + latency-serialized scalar sc1 staging.
// Fixes: (a) each block preloads its weight column-slice into LDS ONCE
// (<=137 KB, 1 block/CU, grid 256 = all co-resident); (b) state is read
// straight from global via 8B agent-scope atomic loads (bypass stale L1/L2,
// served by LLC), software-pipelined depth-8 in registers; same-row lanes
// coalesce to one request. No per-chunk barriers remain.
//
// Sets (blockIdx.x):
//   [0,32)    M1 : m1_new = m1_old@Vm1^T + x_t@Wm1^T          (32 cols/blk)
//   [32,96)   M2 : m2_new = m2_old@Vm2^T + m1_new@Wm2^T       (16 cols/blk)
//   [96,160)  H1 : h1 = .5*h1 + .5*tanh(x@Win1^T + h1@Wh1^T + m2@Wmh1^T + b1)
//   [160,224) H2 : h2 = .5*h2 + .5*tanh(g2a + h1@Win2^T + m2@Wmh2^T)  (+out)
//   [224,256) G2 : g2a = h2_old@Wh2^T + b2                    (32 cols/blk)

#define BB 32
#define TT 2048
#define II 64
#define MM 1024
#define HHH 1024
#define ALEAK 0.5f
#define NTHREADS 512
#define SPIN_CAP 50000
#define BM (BB * MM)

// LDS layout (floats):
//  16-col sets: W[c][k] at c*2052 + k (k<2048, two matrices concatenated)
//               x-weights (H1 only) at 16*2052 + c*68
//  32-col sets: W[c][k] at c*1028 + k (k<1024)
//               x-weights (M1 only) at 32*1028 + c*68
#define DYN_LDS_BYTES 140288  // (32*1028 + 32*68) * 4 = max over sets

#define SCOPE __HIP_MEMORY_SCOPE_AGENT

__device__ __forceinline__ float lda(const float* p) {
  return __hip_atomic_load(p, __ATOMIC_RELAXED, SCOPE);
}
__device__ __forceinline__ void sta(float* p, float v) {
  __hip_atomic_store(p, v, __ATOMIC_RELAXED, SCOPE);
}
__device__ __forceinline__ float2 lda2(const float* p) {
  unsigned long long u =
      __hip_atomic_load((const unsigned long long*)p, __ATOMIC_RELAXED, SCOPE);
  union { unsigned long long u; float2 f; } c;
  c.u = u;
  return c.f;
}

// lane0 spins on an agent-scope flag; capped so a sync bug can't hang the GPU.
__device__ __forceinline__ void wait_flag(int* f, int target) {
  if (threadIdx.x == 0) {
    int it = 0;
    while (__hip_atomic_load(f, __ATOMIC_RELAXED, SCOPE) < target) {
      __builtin_amdgcn_s_sleep(2);
      if (++it > SPIN_CAP) break;  // fail loud (wrong answer), not a hang
    }
  }
  __syncthreads();
}

__device__ __forceinline__ void post_flag(int* f) {
  __syncthreads();  // drains each wave's vmcnt -> all sc1 stores at LLC
  if (threadIdx.x == 0) {
    __hip_atomic_fetch_add(f, 1, __ATOMIC_RELEASE, SCOPE);
  }
}

// ---------------- weight preload into LDS ----------------
// 16-col sets: rows n=nbase+c of Wa (k<1024) and Wb (k>=1024) -> c*2052+k
__device__ void preload16(float* ldsf, const float* __restrict__ Wa,
                          const float* __restrict__ Wb, int nbase) {
  const float4* A = (const float4*)Wa;
  const float4* B = (const float4*)Wb;
  for (int idx = threadIdx.x; idx < 16 * 512; idx += NTHREADS) {
    int c = idx >> 9, q = idx & 511;  // q: float4 index within 2048 floats
    int n = nbase + c;
    float4 v = (q < 256) ? A[(size_t)n * 256 + q] : B[(size_t)n * 256 + (q - 256)];
    *(float4*)(ldsf + c * 2052 + q * 4) = v;
  }
}
// 32-col sets: rows n=nbase+c of W (k<1024) -> c*1028+k
__device__ void preload32(float* ldsf, const float* __restrict__ W, int nbase) {
  const float4* A = (const float4*)W;
  for (int idx = threadIdx.x; idx < 32 * 256; idx += NTHREADS) {
    int c = idx >> 8, q = idx & 255;
    *(float4*)(ldsf + c * 1028 + q * 4) = A[(size_t)(nbase + c) * 256 + q];
  }
}
// input-projection weights (K=64): rows n=nbase+c -> ldsx + c*68
__device__ void preloadX(float* ldsx, const float* __restrict__ W, int nbase,
                         int ncols) {
  const float4* A = (const float4*)W;
  for (int idx = threadIdx.x; idx < ncols * 16; idx += NTHREADS) {
    int c = idx >> 4, q = idx & 15;
    *(float4*)(ldsx + c * 68 + q * 4) = A[(size_t)(nbase + c) * 16 + q];
  }
}

// ---------------- inner dot products ----------------
// K=1024 dot: state row from global (8B coherent loads, depth-8 register
// pipeline = 128 k-values in flight), weights from LDS (b128, 2-way max).
__device__ __forceinline__ float dot1024(const float* __restrict__ srow,
                                         const float* __restrict__ wlds) {
  float2 buf[8][8];
#pragma unroll
  for (int j = 0; j < 8; ++j) {
#pragma unroll
    for (int i = 0; i < 8; ++i) buf[j][i] = lda2(srow + j * 16 + i * 2);
  }
  float a0 = 0.f, a1 = 0.f, a2 = 0.f, a3 = 0.f;
#pragma unroll 8
  for (int kc = 0; kc < 64; ++kc) {
    const int j = kc & 7;  // compile-time within the unrolled body
    const float* w = wlds + kc * 16;
    float4 w0 = *(const float4*)(w);
    float4 w1 = *(const float4*)(w + 4);
    float4 w2 = *(const float4*)(w + 8);
    float4 w3 = *(const float4*)(w + 12);
    a0 = fmaf(w0.x, buf[j][0].x, a0); a0 = fmaf(w0.y, buf[j][0].y, a0);
    a1 = fmaf(w0.z, buf[j][1].x, a1); a1 = fmaf(w0.w, buf[j][1].y, a1);
    a2 = fmaf(w1.x, buf[j][2].x, a2); a2 = fmaf(w1.y, buf[j][2].y, a2);
    a3 = fmaf(w1.z, buf[j][3].x, a3); a3 = fmaf(w1.w, buf[j][3].y, a3);
    a0 = fmaf(w2.x, buf[j][4].x, a0); a0 = fmaf(w2.y, buf[j][4].y, a0);
    a1 = fmaf(w2.z, buf[j][5].x, a1); a1 = fmaf(w2.w, buf[j][5].y, a1);
    a2 = fmaf(w3.x, buf[j][6].x, a2); a2 = fmaf(w3.y, buf[j][6].y, a2);
    a3 = fmaf(w3.z, buf[j][7].x, a3); a3 = fmaf(w3.w, buf[j][7].y, a3);
    if (kc < 56) {  // prefetch chunk kc+8
      const float* s2 = srow + kc * 16 + 128;
#pragma unroll
      for (int i = 0; i < 8; ++i) buf[j][i] = lda2(s2 + i * 2);
    }
  }
  return (a0 + a1) + (a2 + a3);
}

// K=64 input projection: x row from global (cached, read-only), W from LDS.
__device__ __forceinline__ float xdot(const float* __restrict__ xrow,
                                      const float* __restrict__ wx) {
  float a = 0.f;
#pragma unroll
  for (int q = 0; q < 16; ++q) {
    float4 xv = *(const float4*)(xrow + q * 4);
    float4 wv = *(const float4*)(wx + q * 4);
    a = fmaf(xv.x, wv.x, a); a = fmaf(xv.y, wv.y, a);
    a = fmaf(xv.z, wv.z, a); a = fmaf(xv.w, wv.w, a);
  }
  return a;
}

__global__ __launch_bounds__(NTHREADS, 2) void drmn_persistent(
    const float* __restrict__ x, const float* __restrict__ Wm1,
    const float* __restrict__ Vm1, const float* __restrict__ Wm2,
    const float* __restrict__ Vm2, const float* __restrict__ Win1,
    const float* __restrict__ Wh1, const float* __restrict__ Wmh1,
    const float* __restrict__ b1, const float* __restrict__ Win2,
    const float* __restrict__ Wh2, const float* __restrict__ Wmh2,
    const float* __restrict__ b2, float* __restrict__ out, float* ws,
    int* flags) {
  extern __shared__ float ldsf[];
  const int blk = blockIdx.x;
  const int tid = threadIdx.x;

  float* m1s = ws;                 // [2][B][M]
  float* m2s = m1s + 2 * BM;       // [2][B][M]
  float* h1s = m2s + 2 * BM;       // [2][B][H]
  float* h2s = h1s + 2 * BM;       // [2][B][H]
  float* g2a = h2s + 2 * BM;       // [B][H]

  int* m1c = flags;  // each [T]
  int* m2c = m1c + TT;
  int* h1c = m2c + TT;
  int* h2c = h1c + TT;
  int* g2c = h2c + TT;

  if (blk < 32) {
    // ================= M1 (32 cols/blk, rows rg & rg+16 per thread) ======
    const int c = tid & 31, rg = tid >> 5;  // rg 0..15
    const int n = blk * 32 + c;
    preload32(ldsf, Vm1, blk * 32);
    preloadX(ldsf + 32 * 1028, Wm1, blk * 32, 32);
    __syncthreads();
    const float* wcol = ldsf + c * 1028;
    const float* wx = ldsf + 32 * 1028 + c * 68;
    for (int t = 0; t < TT; ++t) {
      const float* rd = m1s + (t & 1) * BM;
      float* wr = m1s + ((t & 1) ^ 1) * BM;
      if (t >= 1) wait_flag(&m1c[t - 1], 32);  // full prev state readable
      if (t >= 2) wait_flag(&m2c[t - 2], 64);  // write-slot consumer done
      float a0 = xdot(x + ((size_t)rg * TT + t) * II, wx);
      float a1 = xdot(x + ((size_t)(rg + 16) * TT + t) * II, wx);
      a0 += dot1024(rd + (size_t)rg * MM, wcol);
      a1 += dot1024(rd + (size_t)(rg + 16) * MM, wcol);
      sta(wr + (size_t)rg * MM + n, a0);
      sta(wr + (size_t)(rg + 16) * MM + n, a1);
      post_flag(&m1c[t]);
    }
  } else if (blk < 96) {
    // ================= M2 (16 cols/blk) =================
    const int sb = blk - 32;
    const int c = tid & 15, r = tid >> 4;  // r 0..31
    const int n = sb * 16 + c;
    preload16(ldsf, Vm2, Wm2, sb * 16);  // Vm2 k<1024, Wm2 k>=1024
    __syncthreads();
    const float* wcol = ldsf + c * 2052;
    for (int t = 0; t < TT; ++t) {
      const float* rd = m2s + (t & 1) * BM;
      float* wr = m2s + ((t & 1) ^ 1) * BM;
      const float* rdm1 = m1s + ((t & 1) ^ 1) * BM;  // m1_new (this tick)
      if (t >= 1) wait_flag(&m2c[t - 1], 64);
      if (t >= 2) {
        wait_flag(&h1c[t - 2], 64);
        wait_flag(&h2c[t - 2], 64);
      }
      float a = dot1024(rd + (size_t)r * MM, wcol);  // Vm2 part
      wait_flag(&m1c[t], 32);
      a += dot1024(rdm1 + (size_t)r * MM, wcol + 1024);  // Wm2 part
      sta(wr + (size_t)r * MM + n, a);
      post_flag(&m2c[t]);
    }
  } else if (blk < 160) {
    // ================= H1 (16 cols/blk) =================
    const int sb = blk - 96;
    const int c = tid & 15, r = tid >> 4;
    const int n = sb * 16 + c;
    preload16(ldsf, Wh1, Wmh1, sb * 16);  // Wh1 k<1024, Wmh1 k>=1024
    preloadX(ldsf + 16 * 2052, Win1, sb * 16, 16);
    __syncthreads();
    const float* wcol = ldsf + c * 2052;
    const float* wx = ldsf + 16 * 2052 + c * 68;
    const float bias = b1[n];
    float h1reg = 0.f;  // own h1[r][n]
    for (int t = 0; t < TT; ++t) {
      const float* rdh = h1s + (t & 1) * BM;            // h1[t-1]
      float* wrh = h1s + ((t & 1) ^ 1) * BM;
      const float* rdm2 = m2s + ((t & 1) ^ 1) * BM;     // m2[t]
      if (t >= 1) wait_flag(&h1c[t - 1], 64);
      if (t >= 2) wait_flag(&h2c[t - 2], 64);
      float a = bias + xdot(x + ((size_t)r * TT + t) * II, wx);
      wait_flag(&m2c[t], 64);
      a += dot1024(rdm2 + (size_t)r * MM, wcol + 1024);  // Wmh1 part first
      a += dot1024(rdh + (size_t)r * MM, wcol);          // Wh1 part
      float h1n = (1.0f - ALEAK) * h1reg + ALEAK * tanhf(a);
      h1reg = h1n;
      sta(wrh + (size_t)r * MM + n, h1n);
      post_flag(&h1c[t]);
    }
  } else if (blk < 224) {
    // ================= H2 main (16 cols/blk) =================
    const int sb = blk - 160;
    const int c = tid & 15, r = tid >> 4;
    const int n = sb * 16 + c;
    preload16(ldsf, Wmh2, Win2, sb * 16);  // Wmh2 k<1024, Win2 k>=1024
    __syncthreads();
    const float* wcol = ldsf + c * 2052;
    float h2reg = 0.f;  // own h2[r][n]
    for (int t = 0; t < TT; ++t) {
      float* wrh = h2s + ((t & 1) ^ 1) * BM;
      const float* rdm2 = m2s + ((t & 1) ^ 1) * BM;   // m2[t]
      const float* rdh1 = h1s + ((t & 1) ^ 1) * BM;   // h1[t]
      wait_flag(&m2c[t], 64);
      float a = dot1024(rdm2 + (size_t)r * MM, wcol);  // Wmh2 part
      wait_flag(&h1c[t], 64);
      a += dot1024(rdh1 + (size_t)r * MM, wcol + 1024);  // Win2 part
      wait_flag(&g2c[t], 32);
      a += lda(g2a + (size_t)r * MM + n);
      float h2n = (1.0f - ALEAK) * h2reg + ALEAK * tanhf(a);
      h2reg = h2n;
      sta(wrh + (size_t)r * MM + n, h2n);
      out[((size_t)r * TT + t) * HHH + n] = h2n;  // visible at kernel end
      post_flag(&h2c[t]);
    }
  } else {
    // ================= G2 (Wh2 partial, 32 cols/blk) =================
    const int sb = blk - 224;
    const int c = tid & 31, rg = tid >> 5;  // rg 0..15
    const int n = sb * 32 + c;
    preload32(ldsf, Wh2, sb * 32);
    __syncthreads();
    const float* wcol = ldsf + c * 1028;
    const float bias = b2[n];
    for (int t = 0; t < TT; ++t) {
      const float* rdh = h2s + (t & 1) * BM;  // h2[t-1]
      if (t >= 1) wait_flag(&h2c[t - 1], 64);  // also: g2a consumer done
      float a0 = bias + dot1024(rdh + (size_t)rg * MM, wcol);
      float a1 = bias + dot1024(rdh + (size_t)(rg + 16) * MM, wcol);
      sta(g2a + (size_t)rg * MM + n, a0);
      sta(g2a + (size_t)(rg + 16) * MM + n, a1);
      post_flag(&g2c[t]);
    }
  }
}

extern "C" void kernel_launch(void* const* d_in, const int* in_sizes, int n_in,
                              void* d_out, int out_size, void* d_ws,
                              size_t ws_size, hipStream_t stream) {
  const float* xin  = (const float*)d_in[0];
  const float* Wm1  = (const float*)d_in[1];
  const float* Vm1  = (const float*)d_in[2];
  const float* Wm2  = (const float*)d_in[3];
  const float* Vm2  = (const float*)d_in[4];
  const float* Win1 = (const float*)d_in[5];
  const float* Wh1  = (const float*)d_in[6];
  const float* Wmh1 = (const float*)d_in[7];
  const float* b1   = (const float*)d_in[8];
  const float* Win2 = (const float*)d_in[9];
  const float* Wh2  = (const float*)d_in[10];
  const float* Wmh2 = (const float*)d_in[11];
  const float* b2   = (const float*)d_in[12];
  float* out = (float*)d_out;

  float* ws = (float*)d_ws;
  const size_t data_floats = (size_t)8 * BB * MM + (size_t)BB * HHH;
  int* flags = (int*)(ws + data_floats);
  const size_t clear_bytes =
      data_floats * sizeof(float) + (size_t)5 * TT * sizeof(int);
  hipMemsetAsync(d_ws, 0, clear_bytes, stream);  // zero states + flags

  // opt-in to >64KB dynamic LDS (idempotent; no stream op, capture-safe)
  hipFuncSetAttribute((const void*)drmn_persistent,
                      hipFuncAttributeMaxDynamicSharedMemorySize,
                      DYN_LDS_BYTES);

  drmn_persistent<<<256, NTHREADS, DYN_LDS_BYTES, stream>>>(
      xin, Wm1, Vm1, Wm2, Vm2, Win1, Wh1, Wmh1, b1, Win2, Wh2, Wmh2, b2, out,
      ws, flags);
}